// Round 7
// baseline (1364.904 us; speedup 1.0000x reference)
//
#include <hip/hip_runtime.h>
#include <stdint.h>

#define T_    16
#define N_    2048
#define CAP_  96

typedef float v4 __attribute__((ext_vector_type(4)));

__device__ inline float frcp(float x){
#if __has_builtin(__builtin_amdgcn_rcpf)
  return __builtin_amdgcn_rcpf(x);
#else
  return 1.0f / x;
#endif
}
__device__ inline float fsig(float x){ return frcp(1.0f + __expf(-x)); }
__device__ inline float rdlane(float v, int k){
  return __int_as_float(__builtin_amdgcn_readlane(__float_as_int(v), k));
}

// ---------------------------------------------------------------- mask build + cnt zero
__global__ __launch_bounds__(256) void k_mask(const uint8_t* __restrict__ ego_raw,
                                              float* __restrict__ m,
                                              int* __restrict__ cnt){
  __shared__ int s_int01, s_f01;
  const int tid = threadIdx.x;
  if (tid == 0){ s_int01 = 1; s_f01 = 1; }
  __syncthreads();
  const uint32_t* w = (const uint32_t*)ego_raw;
  int int01 = 1, f01 = 1;
  for (int i = tid; i < 8192; i += 256){
    uint32_t v = w[i];
    int01 &= (v <= 1u);
    f01   &= (v == 0u) || (v == 0x3F800000u);
  }
  if (!int01) atomicAnd(&s_int01, 0);
  if (!f01)   atomicAnd(&s_f01, 0);
  __syncthreads();
  const int mode = s_int01 ? 0 : (s_f01 ? 1 : 2); // 0:int32 1:f32 2:byte
  const int base = blockIdx.x * 2048;
  for (int q = tid; q < 2048; q += 256){
    int i = base + q;
    int t = i >> 11, n = i & 2047, b = n >> 8, j = n & 255;
    int src = (b*T_ + t)*256 + j;
    float val;
    if (mode == 0)      val = (((const int32_t*)ego_raw)[src] != 0)   ? 1.f : 0.f;
    else if (mode == 1) val = (((const float*)ego_raw)[src]  != 0.f)  ? 1.f : 0.f;
    else                val = (ego_raw[src] != 0)                     ? 1.f : 0.f;
    m[i] = val;
    cnt[i] = 0;
  }
}

// ---------------------------------------------------------------- sparsify adj into CSC lists
__global__ __launch_bounds__(256) void k_sparsify(const float* __restrict__ adj,
                                                  int* __restrict__ cnt,
                                                  uint16_t* __restrict__ idx){
  const int bx = blockIdx.x;           // 1024 blocks
  const int t  = bx >> 6;              // 0..15
  const int sg = bx & 63;              // 0..63, 32 s-rows each
  const int tid = threadIdx.x;
  const int tcol = t << 11;
  const float4* base4 = (const float4*)(adj + ((size_t)t << 22));
  for (int sr = 0; sr < 32; sr++){
    int s = (sg << 5) + sr;
    const float4* row4 = base4 + ((size_t)s << 9);
    #pragma unroll
    for (int ii = 0; ii < 2; ii++){
      float4 v = row4[(ii << 8) + tid];
      int d = ((ii << 8) + tid) << 2;
      if (v.x != 0.f){ int p = atomicAdd(&cnt[tcol+d  ],1); if (p<CAP_) idx[(size_t)(tcol+d  )*CAP_+p]=(uint16_t)s; }
      if (v.y != 0.f){ int p = atomicAdd(&cnt[tcol+d+1],1); if (p<CAP_) idx[(size_t)(tcol+d+1)*CAP_+p]=(uint16_t)s; }
      if (v.z != 0.f){ int p = atomicAdd(&cnt[tcol+d+2],1); if (p<CAP_) idx[(size_t)(tcol+d+2)*CAP_+p]=(uint16_t)s; }
      if (v.w != 0.f){ int p = atomicAdd(&cnt[tcol+d+3],1); if (p<CAP_) idx[(size_t)(tcol+d+3)*CAP_+p]=(uint16_t)s; }
    }
  }
}

// ---------------------------------------------------------------- dinv
__global__ __launch_bounds__(256) void k_dinv(const int* __restrict__ cnt,
                                              const uint16_t* __restrict__ idx,
                                              const float* __restrict__ m,
                                              float* __restrict__ dinv){
  const int col = blockIdx.x*256 + threadIdx.x;
  int c = cnt[col]; if (c > CAP_) c = CAP_;
  const int tbase = col & ~2047;
  const uint16_t* lst = idx + (size_t)col*CAP_;
  float s = 1.0f;                       // self-loop
  for (int i = 0; i < c; i++) s += m[tbase + lst[i]];
  dinv[col] = (m[col] > 0.5f) ? rsqrtf(s) : 0.f;
}

// ---------------------------------------------------------------- layer 1 fused: h1 = relu(dinv*Σ dinv_s*(x_s@W1) + b1)
__global__ __launch_bounds__(256) void k_gcn1(const float* __restrict__ x,
                                              const float* __restrict__ W1,
                                              const float* __restrict__ b1,
                                              const int* __restrict__ cnt,
                                              const uint16_t* __restrict__ idx,
                                              const float* __restrict__ dinv,
                                              float* __restrict__ h1){
  const int col = blockIdx.x*4 + (threadIdx.x >> 6);
  const int lane = threadIdx.x & 63;
  int c = cnt[col]; if (c > CAP_) c = CAP_;
  const int tbase = col & ~2047;
  const uint16_t* lst = idx + (size_t)col*CAP_;
  const float w1a = W1[lane], w1b = W1[64 + lane];
  const float2* x2 = (const float2*)x;
  float2 xs = x2[col];
  float acc = dinv[col]*(xs.x*w1a + xs.y*w1b);     // self-loop
  for (int i = 0; i < c; i++){
    int s = tbase + lst[i];
    float ds = dinv[s];
    float2 xv = x2[s];
    acc += ds*(xv.x*w1a + xv.y*w1b);
  }
  float y = dinv[col]*acc + b1[lane];
  h1[(size_t)col*64 + lane] = fmaxf(y, 0.f);
}

// ---------------------------------------------------------------- v2 = dinv * (h1 @ W2)
__global__ __launch_bounds__(256) void k_v2(const float* __restrict__ h1,
                                            const float* __restrict__ W2,
                                            const float* __restrict__ dinv,
                                            float* __restrict__ v2){
  const int gid = blockIdx.x*256 + threadIdx.x;   // node*64 + hp
  const int hp = gid & 63, node = gid >> 6;
  const float* row = h1 + (size_t)node*64;
  float s = 0.f;
  #pragma unroll 8
  for (int h = 0; h < 64; h++) s += row[h]*W2[h*64 + hp];
  v2[gid] = dinv[node]*s;
}

// ---------------------------------------------------------------- layer 2 aggregation: h2 = m * (dinv*Σ v2 + b2)
__global__ __launch_bounds__(256) void k_agg2(const float* __restrict__ v,
                                              const int* __restrict__ cnt,
                                              const uint16_t* __restrict__ idx,
                                              const float* __restrict__ dinv,
                                              const float* __restrict__ m,
                                              const float* __restrict__ b2,
                                              float* __restrict__ h2){
  const int col = blockIdx.x*4 + (threadIdx.x >> 6);
  const int lane = threadIdx.x & 63;
  int c = cnt[col]; if (c > CAP_) c = CAP_;
  const int tbase = col & ~2047;
  const uint16_t* lst = idx + (size_t)col*CAP_;
  float acc = v[(size_t)col*64 + lane];            // self-loop
  for (int i = 0; i < c; i++){
    int s = lst[i];
    acc += v[((size_t)tbase + s)*64 + lane];
  }
  float y = dinv[col]*acc + b2[lane];
  h2[(size_t)col*64 + lane] = m[col]*y;
}

// ---------------------------------------------------------------- P4[tn][j][gate] pre-activations
// Weights as 16 named v4 + asm VGPR-pin (indexed wr[64] array was living in
// scratch: VGPR_Count 84 < footprint — reloaded 256B/thread/row).
__global__ __attribute__((amdgpu_flat_work_group_size(256,256), amdgpu_waves_per_eu(1)))
void k_lstmpre(const float* __restrict__ h2,
               const float* __restrict__ Wih,
               const float* __restrict__ bih,
               const float* __restrict__ bhh,
               float* __restrict__ P4){
  const int tid = threadIdx.x;
  const int j = tid & 127;                         // gate row 0..127
  const int half = tid >> 7;                       // 0/1
  const int tn0 = blockIdx.x*64 + half*32;
  const v4* wsrc = (const v4*)(Wih + j*64);
#define LWP(Q) v4 u##Q = wsrc[Q]; asm("" : "+v"(u##Q));
  LWP(0)  LWP(1)  LWP(2)  LWP(3)  LWP(4)  LWP(5)  LWP(6)  LWP(7)
  LWP(8)  LWP(9)  LWP(10) LWP(11) LWP(12) LWP(13) LWP(14) LWP(15)
#undef LWP
  const float bj = bih[j] + bhh[j];
  const int dst = (j & 31)*4 + (j >> 5);           // interleaved {i,f,g,o} per jj
  for (int r = 0; r < 32; r++){
    int tn = tn0 + r;
    const v4* row = (const v4*)(h2 + (size_t)tn*64);
    float a0 = bj, a1 = 0.f, a2 = 0.f, a3 = 0.f;
#define ACC(Q){ v4 hv = row[Q]; \
    a0 = fmaf(u##Q.x, hv.x, a0); a1 = fmaf(u##Q.y, hv.y, a1); \
    a2 = fmaf(u##Q.z, hv.z, a2); a3 = fmaf(u##Q.w, hv.w, a3); }
    ACC(0)  ACC(1)  ACC(2)  ACC(3)  ACC(4)  ACC(5)  ACC(6)  ACC(7)
    ACC(8)  ACC(9)  ACC(10) ACC(11) ACC(12) ACC(13) ACC(14) ACC(15)
#undef ACC
    P4[(size_t)tn*128 + dst] = (a0 + a1) + (a2 + a3);
  }
}

// ---------------------------------------------------------------- LSTM scan: 16 chains, 1 wave each
// Root cause of R1–R6 plateau: scheduler rematerialized the 128 weight loads
// inside the loop (VGPR_Count 44–84 « footprint). Fix: waves_per_eu(1,1)
// raises the RA budget to ~512 VGPRs, and an opaque asm "+v" pin on each
// named v4 weight forbids sinking/remat. Tell: VGPR_Count must jump to ~170+.
__global__ __attribute__((amdgpu_flat_work_group_size(64,64), amdgpu_waves_per_eu(1,1)))
void k_lstm(const float* __restrict__ P4,
            const float* __restrict__ Whh,
            float* __restrict__ L64){
  const int t = blockIdx.x;       // chain 0..15
  const int l = threadIdx.x;      // 0..63
  const int j = l & 31;
  const float* Wi = Whh + (size_t)j*32;
  const float* Wf = Wi + 32*32;
  const float* Wg = Wi + 64*32;
  const float* Wo = Wi + 96*32;
#define LW(K) v4 w##K = (v4){ Wi[K], Wf[K], Wg[K], Wo[K] }; asm("" : "+v"(w##K));
  LW(0)  LW(1)  LW(2)  LW(3)  LW(4)  LW(5)  LW(6)  LW(7)
  LW(8)  LW(9)  LW(10) LW(11) LW(12) LW(13) LW(14) LW(15)
  LW(16) LW(17) LW(18) LW(19) LW(20) LW(21) LW(22) LW(23)
  LW(24) LW(25) LW(26) LW(27) LW(28) LW(29) LW(30) LW(31)
#undef LW
  const float4* Pt = (const float4*)P4 + (size_t)t*N_*32 + j;
  float* Lt = L64 + (size_t)t*N_*64;
  float c = 0.f, hn = 0.f;
  float4 p0 = Pt[0], p1 = Pt[32];
  for (int n = 0; n < N_; n++){
    float4 cur = p0; p0 = p1;
    int np = (n + 2 < N_) ? (n + 2) : (N_ - 1);
    p1 = Pt[(size_t)np*32];
    v4 a0 = (v4){0.f,0.f,0.f,0.f}, a1 = a0, a2 = a0, a3 = a0;
#define ST(K, ACC) { float hh = rdlane(hn, K); \
      ACC = __builtin_elementwise_fma(w##K, (v4){hh,hh,hh,hh}, ACC); }
    ST(0,a0)  ST(1,a1)  ST(2,a2)  ST(3,a3)
    ST(4,a0)  ST(5,a1)  ST(6,a2)  ST(7,a3)
    ST(8,a0)  ST(9,a1)  ST(10,a2) ST(11,a3)
    ST(12,a0) ST(13,a1) ST(14,a2) ST(15,a3)
    ST(16,a0) ST(17,a1) ST(18,a2) ST(19,a3)
    ST(20,a0) ST(21,a1) ST(22,a2) ST(23,a3)
    ST(24,a0) ST(25,a1) ST(26,a2) ST(27,a3)
    ST(28,a0) ST(29,a1) ST(30,a2) ST(31,a3)
#undef ST
    v4 s = (a0 + a1) + (a2 + a3);
    float gi = cur.x + s.x;
    float gf = cur.y + s.y;
    float gg = cur.z + s.z;
    float go = cur.w + s.w;
    float iv = fsig(gi);
    float fv = fsig(gf);
    float gv = fmaf(2.0f, fsig(2.0f*gg), -1.0f);   // tanh
    float ov = fsig(go);
    c = fmaf(fv, c, iv*gv);
    float th = fmaf(2.0f, fsig(2.0f*c), -1.0f);    // tanh(c)
    hn = ov*th;
    Lt[n*64 + l] = hn;                             // full-wave 256B store
  }
}

// ---------------------------------------------------------------- scores[t*2048+n] = lstm[t,n,:]@Wa
__global__ __launch_bounds__(256) void k_score(const float* __restrict__ L64,
                                               const float* __restrict__ Wa,
                                               float* __restrict__ scores){
  const int gid = blockIdx.x*256 + threadIdx.x;   // t*2048 + n, 32768 total
  const float4* row = (const float4*)(L64 + (size_t)gid*64);
  const float4* wa4 = (const float4*)Wa;
  float s = 0.f;
  #pragma unroll
  for (int q = 0; q < 8; q++){
    float4 hv = row[q], wv = wa4[q];
    s += hv.x*wv.x + hv.y*wv.y + hv.z*wv.z + hv.w*wv.w;
  }
  scores[gid] = s;
}

// ---------------------------------------------------------------- softmax attention pool
__global__ __launch_bounds__(256) void k_attn(const float* __restrict__ scores,
                                              const float* __restrict__ L64,
                                              float* __restrict__ out){
  const int gid = blockIdx.x*256 + threadIdx.x;   // n*32 + k
  const int k = gid & 31, n = gid >> 5;
  float sc[16]; float mx = -1e30f;
  #pragma unroll
  for (int t = 0; t < 16; t++){ float v = scores[(t << 11) + n]; sc[t] = v; mx = fmaxf(mx, v); }
  float sum = 0.f;
  #pragma unroll
  for (int t = 0; t < 16; t++){ float e = __expf(sc[t] - mx); sc[t] = e; sum += e; }
  const float inv = frcp(sum);
  float acc = 0.f;
  #pragma unroll
  for (int t = 0; t < 16; t++) acc += sc[t]*L64[((size_t)((t << 11) + n))*64 + k];
  out[gid] = acc*inv;
}

// ---------------------------------------------------------------- launch
extern "C" void kernel_launch(void* const* d_in, const int* in_sizes, int n_in,
                              void* d_out, int out_size, void* d_ws, size_t ws_size,
                              hipStream_t stream){
  (void)in_sizes; (void)n_in; (void)out_size; (void)ws_size;
  const float*   x   = (const float*)d_in[0];
  const float*   adj = (const float*)d_in[1];
  const uint8_t* ego = (const uint8_t*)d_in[2];
  const float*   W1  = (const float*)d_in[3];
  const float*   b1  = (const float*)d_in[4];
  const float*   W2  = (const float*)d_in[5];
  const float*   b2  = (const float*)d_in[6];
  const float*   Wih = (const float*)d_in[7];
  const float*   Whh = (const float*)d_in[8];
  const float*   bih = (const float*)d_in[9];
  const float*   bhh = (const float*)d_in[10];
  const float*   Wa  = (const float*)d_in[11];
  // d_in[12] = ba: softmax is shift-invariant, unused
  float* out = (float*)d_out;
  char* ws = (char*)d_ws;

  float*    m      = (float*)(ws);                  // 128 KB
  float*    dinv   = (float*)(ws + 131072);         // 128 KB
  int*      cnt    = (int*)  (ws + 262144);         // 128 KB
  uint16_t* idx    = (uint16_t*)(ws + 393216);      // 6 MB
  float*    v      = (float*)(ws + 6684672);        // 8 MB   (v2; later reused as L64)
  float*    h      = (float*)(ws + 15073280);       // 8 MB   (h1 then h2; later scores)
  float*    P4     = (float*)(ws + 23461888);       // 16 MB
  float*    L64    = v;                             // v dead after k_agg2
  float*    scores = h;                             // h dead after k_lstmpre

  k_mask    <<<16,    256, 0, stream>>>(ego, m, cnt);
  k_sparsify<<<1024,  256, 0, stream>>>(adj, cnt, idx);
  k_dinv    <<<128,   256, 0, stream>>>(cnt, idx, m, dinv);
  k_gcn1    <<<8192,  256, 0, stream>>>(x, W1, b1, cnt, idx, dinv, h);
  k_v2      <<<8192,  256, 0, stream>>>(h, W2, dinv, v);
  k_agg2    <<<8192,  256, 0, stream>>>(v, cnt, idx, dinv, m, b2, h);
  k_lstmpre <<<512,   256, 0, stream>>>(h, Wih, bih, bhh, P4);
  k_lstm    <<<16,    64,  0, stream>>>(P4, Whh, L64);
  k_score   <<<128,   256, 0, stream>>>(L64, Wa, scores);
  k_attn    <<<256,   256, 0, stream>>>(scores, L64, out);
}

// Round 8
// 1129.509 us; speedup vs baseline: 1.2084x; 1.2084x over previous
//
#include <hip/hip_runtime.h>
#include <stdint.h>

#define T_    16
#define N_    2048
#define CAP_  96

typedef float v4 __attribute__((ext_vector_type(4)));
typedef float f32x4 __attribute__((ext_vector_type(4)));
typedef _Float16 f16x8 __attribute__((ext_vector_type(8)));

__device__ inline float frcp(float x){
#if __has_builtin(__builtin_amdgcn_rcpf)
  return __builtin_amdgcn_rcpf(x);
#else
  return 1.0f / x;
#endif
}
__device__ inline float fsig(float x){ return frcp(1.0f + __expf(-x)); }

// ---------------------------------------------------------------- mask build + cnt zero
__global__ __launch_bounds__(256) void k_mask(const uint8_t* __restrict__ ego_raw,
                                              float* __restrict__ m,
                                              int* __restrict__ cnt){
  __shared__ int s_int01, s_f01;
  const int tid = threadIdx.x;
  if (tid == 0){ s_int01 = 1; s_f01 = 1; }
  __syncthreads();
  const uint32_t* w = (const uint32_t*)ego_raw;
  int int01 = 1, f01 = 1;
  for (int i = tid; i < 8192; i += 256){
    uint32_t v = w[i];
    int01 &= (v <= 1u);
    f01   &= (v == 0u) || (v == 0x3F800000u);
  }
  if (!int01) atomicAnd(&s_int01, 0);
  if (!f01)   atomicAnd(&s_f01, 0);
  __syncthreads();
  const int mode = s_int01 ? 0 : (s_f01 ? 1 : 2); // 0:int32 1:f32 2:byte
  const int base = blockIdx.x * 2048;
  for (int q = tid; q < 2048; q += 256){
    int i = base + q;
    int t = i >> 11, n = i & 2047, b = n >> 8, j = n & 255;
    int src = (b*T_ + t)*256 + j;
    float val;
    if (mode == 0)      val = (((const int32_t*)ego_raw)[src] != 0)   ? 1.f : 0.f;
    else if (mode == 1) val = (((const float*)ego_raw)[src]  != 0.f)  ? 1.f : 0.f;
    else                val = (ego_raw[src] != 0)                     ? 1.f : 0.f;
    m[i] = val;
    cnt[i] = 0;
  }
}

// ---------------------------------------------------------------- sparsify adj into CSC lists
__global__ __launch_bounds__(256) void k_sparsify(const float* __restrict__ adj,
                                                  int* __restrict__ cnt,
                                                  uint16_t* __restrict__ idx){
  const int bx = blockIdx.x;           // 1024 blocks
  const int t  = bx >> 6;              // 0..15
  const int sg = bx & 63;              // 0..63, 32 s-rows each
  const int tid = threadIdx.x;
  const int tcol = t << 11;
  const float4* base4 = (const float4*)(adj + ((size_t)t << 22));
  for (int sr = 0; sr < 32; sr++){
    int s = (sg << 5) + sr;
    const float4* row4 = base4 + ((size_t)s << 9);
    #pragma unroll
    for (int ii = 0; ii < 2; ii++){
      float4 v = row4[(ii << 8) + tid];
      int d = ((ii << 8) + tid) << 2;
      if (v.x != 0.f){ int p = atomicAdd(&cnt[tcol+d  ],1); if (p<CAP_) idx[(size_t)(tcol+d  )*CAP_+p]=(uint16_t)s; }
      if (v.y != 0.f){ int p = atomicAdd(&cnt[tcol+d+1],1); if (p<CAP_) idx[(size_t)(tcol+d+1)*CAP_+p]=(uint16_t)s; }
      if (v.z != 0.f){ int p = atomicAdd(&cnt[tcol+d+2],1); if (p<CAP_) idx[(size_t)(tcol+d+2)*CAP_+p]=(uint16_t)s; }
      if (v.w != 0.f){ int p = atomicAdd(&cnt[tcol+d+3],1); if (p<CAP_) idx[(size_t)(tcol+d+3)*CAP_+p]=(uint16_t)s; }
    }
  }
}

// ---------------------------------------------------------------- dinv
__global__ __launch_bounds__(256) void k_dinv(const int* __restrict__ cnt,
                                              const uint16_t* __restrict__ idx,
                                              const float* __restrict__ m,
                                              float* __restrict__ dinv){
  const int col = blockIdx.x*256 + threadIdx.x;
  int c = cnt[col]; if (c > CAP_) c = CAP_;
  const int tbase = col & ~2047;
  const uint16_t* lst = idx + (size_t)col*CAP_;
  float s = 1.0f;                       // self-loop
  for (int i = 0; i < c; i++) s += m[tbase + lst[i]];
  dinv[col] = (m[col] > 0.5f) ? rsqrtf(s) : 0.f;
}

// ---------------------------------------------------------------- layer 1 fused: h1 = relu(dinv*Σ dinv_s*(x_s@W1) + b1)
__global__ __launch_bounds__(256) void k_gcn1(const float* __restrict__ x,
                                              const float* __restrict__ W1,
                                              const float* __restrict__ b1,
                                              const int* __restrict__ cnt,
                                              const uint16_t* __restrict__ idx,
                                              const float* __restrict__ dinv,
                                              float* __restrict__ h1){
  const int col = blockIdx.x*4 + (threadIdx.x >> 6);
  const int lane = threadIdx.x & 63;
  int c = cnt[col]; if (c > CAP_) c = CAP_;
  const int tbase = col & ~2047;
  const uint16_t* lst = idx + (size_t)col*CAP_;
  const float w1a = W1[lane], w1b = W1[64 + lane];
  const float2* x2 = (const float2*)x;
  float2 xs = x2[col];
  float acc = dinv[col]*(xs.x*w1a + xs.y*w1b);     // self-loop
  for (int i = 0; i < c; i++){
    int s = tbase + lst[i];
    float ds = dinv[s];
    float2 xv = x2[s];
    acc += ds*(xv.x*w1a + xv.y*w1b);
  }
  float y = dinv[col]*acc + b1[lane];
  h1[(size_t)col*64 + lane] = fmaxf(y, 0.f);
}

// ---------------------------------------------------------------- v2 = dinv * (h1 @ W2)
__global__ __launch_bounds__(256) void k_v2(const float* __restrict__ h1,
                                            const float* __restrict__ W2,
                                            const float* __restrict__ dinv,
                                            float* __restrict__ v2){
  const int gid = blockIdx.x*256 + threadIdx.x;   // node*64 + hp
  const int hp = gid & 63, node = gid >> 6;
  const float* row = h1 + (size_t)node*64;
  float s = 0.f;
  #pragma unroll 8
  for (int h = 0; h < 64; h++) s += row[h]*W2[h*64 + hp];
  v2[gid] = dinv[node]*s;
}

// ---------------------------------------------------------------- layer 2 aggregation: h2 = m * (dinv*Σ v2 + b2)
__global__ __launch_bounds__(256) void k_agg2(const float* __restrict__ v,
                                              const int* __restrict__ cnt,
                                              const uint16_t* __restrict__ idx,
                                              const float* __restrict__ dinv,
                                              const float* __restrict__ m,
                                              const float* __restrict__ b2,
                                              float* __restrict__ h2){
  const int col = blockIdx.x*4 + (threadIdx.x >> 6);
  const int lane = threadIdx.x & 63;
  int c = cnt[col]; if (c > CAP_) c = CAP_;
  const int tbase = col & ~2047;
  const uint16_t* lst = idx + (size_t)col*CAP_;
  float acc = v[(size_t)col*64 + lane];            // self-loop
  for (int i = 0; i < c; i++){
    int s = lst[i];
    acc += v[((size_t)tbase + s)*64 + lane];
  }
  float y = dinv[col]*acc + b2[lane];
  h2[(size_t)col*64 + lane] = m[col]*y;
}

// ---------------------------------------------------------------- P4[tn][j][gate] pre-activations
__global__ __attribute__((amdgpu_flat_work_group_size(256,256), amdgpu_waves_per_eu(1)))
void k_lstmpre(const float* __restrict__ h2,
               const float* __restrict__ Wih,
               const float* __restrict__ bih,
               const float* __restrict__ bhh,
               float* __restrict__ P4){
  const int tid = threadIdx.x;
  const int j = tid & 127;                         // gate row 0..127
  const int half = tid >> 7;                       // 0/1
  const int tn0 = blockIdx.x*64 + half*32;
  const v4* wsrc = (const v4*)(Wih + j*64);
#define LWP(Q) v4 u##Q = wsrc[Q]; asm("" : "+v"(u##Q));
  LWP(0)  LWP(1)  LWP(2)  LWP(3)  LWP(4)  LWP(5)  LWP(6)  LWP(7)
  LWP(8)  LWP(9)  LWP(10) LWP(11) LWP(12) LWP(13) LWP(14) LWP(15)
#undef LWP
  const float bj = bih[j] + bhh[j];
  const int dst = (j & 31)*4 + (j >> 5);           // interleaved {i,f,g,o} per jj
  for (int r = 0; r < 32; r++){
    int tn = tn0 + r;
    const v4* row = (const v4*)(h2 + (size_t)tn*64);
    float a0 = bj, a1 = 0.f, a2 = 0.f, a3 = 0.f;
#define ACC(Q){ v4 hv = row[Q]; \
    a0 = fmaf(u##Q.x, hv.x, a0); a1 = fmaf(u##Q.y, hv.y, a1); \
    a2 = fmaf(u##Q.z, hv.z, a2); a3 = fmaf(u##Q.w, hv.w, a3); }
    ACC(0)  ACC(1)  ACC(2)  ACC(3)  ACC(4)  ACC(5)  ACC(6)  ACC(7)
    ACC(8)  ACC(9)  ACC(10) ACC(11) ACC(12) ACC(13) ACC(14) ACC(15)
#undef ACC
    P4[(size_t)tn*128 + dst] = (a0 + a1) + (a2 + a3);
  }
}

// ---------------------------------------------------------------- LSTM scan: 16 chains, 1 wave each
// Solo-wave issue cadence ≈ 4-5 cyc/instr (R2–R7: time/step ≈ 4-5× VALU count,
// invariant under scalar/pk/scratch/pinned variants) → minimize instructions.
// 8× mfma_f32_16x16x32_f16 compute y^T = h^T·Whh^T:
//   B-frag block b (invariant): Whh[16b+c4][8q+i] f16   (c4=lane&15, q=lane>>4)
//   A-frag = h broadcast: lane needs h[8q..8q+7] f16 — 1 ds_write_b16 + 1 ds_read_b128
//   D (col=lane&15, row=4q+reg, m89-verified): lane holds y[16b+c4] ∀b →
//   j = c4+16(q&1) = l&31 (same as before); gate g = reg0 of block 2g/2g+1 by (l&16)
__global__ __attribute__((amdgpu_flat_work_group_size(64,64), amdgpu_waves_per_eu(1,1)))
void k_lstm(const float* __restrict__ P4,
            const float* __restrict__ Whh,
            float* __restrict__ L64){
  const int t = blockIdx.x;       // chain 0..15
  const int l = threadIdx.x;      // 0..63
  const int c4 = l & 15, q = l >> 4;
  const int j = l & 31;
  // B-frags (loop-invariant), named + pinned
#define LB(B) f16x8 b##B; { const float* wr = Whh + (size_t)(16*B + c4)*32 + 8*q; \
    f16x8 tmp; tmp[0]=(_Float16)wr[0]; tmp[1]=(_Float16)wr[1]; tmp[2]=(_Float16)wr[2]; \
    tmp[3]=(_Float16)wr[3]; tmp[4]=(_Float16)wr[4]; tmp[5]=(_Float16)wr[5]; \
    tmp[6]=(_Float16)wr[6]; tmp[7]=(_Float16)wr[7]; b##B = tmp; } asm("" : "+v"(b##B));
  LB(0) LB(1) LB(2) LB(3) LB(4) LB(5) LB(6) LB(7)
#undef LB
  __shared__ __align__(16) _Float16 hs[32];
  hs[j] = (_Float16)0.f;          // all lanes; duplicates write same value
  const float4* Pt = (const float4*)P4 + (size_t)t*N_*32 + j;
  float* Lt = L64 + (size_t)t*N_*64;
  float c = 0.f;
  const f32x4 zero = {0.f, 0.f, 0.f, 0.f};
  const bool hiq = (l & 16) != 0;
  float4 p0 = Pt[0], p1 = Pt[32];
  for (int n = 0; n < N_; n++){
    float4 cur = p0; p0 = p1;
    int np = (n + 2 < N_) ? (n + 2) : (N_ - 1);
    p1 = Pt[(size_t)np*32];
    f16x8 af = *(const f16x8*)(hs + 8*q);          // ds_read_b128, h[8q..8q+7]
    f32x4 d0 = __builtin_amdgcn_mfma_f32_16x16x32_f16(af, b0, zero, 0, 0, 0);
    f32x4 d1 = __builtin_amdgcn_mfma_f32_16x16x32_f16(af, b1, zero, 0, 0, 0);
    f32x4 d2 = __builtin_amdgcn_mfma_f32_16x16x32_f16(af, b2, zero, 0, 0, 0);
    f32x4 d3 = __builtin_amdgcn_mfma_f32_16x16x32_f16(af, b3, zero, 0, 0, 0);
    f32x4 d4 = __builtin_amdgcn_mfma_f32_16x16x32_f16(af, b4, zero, 0, 0, 0);
    f32x4 d5 = __builtin_amdgcn_mfma_f32_16x16x32_f16(af, b5, zero, 0, 0, 0);
    f32x4 d6 = __builtin_amdgcn_mfma_f32_16x16x32_f16(af, b6, zero, 0, 0, 0);
    f32x4 d7 = __builtin_amdgcn_mfma_f32_16x16x32_f16(af, b7, zero, 0, 0, 0);
    float gi = cur.x + (hiq ? d1[0] : d0[0]);
    float gf = cur.y + (hiq ? d3[0] : d2[0]);
    float gg = cur.z + (hiq ? d5[0] : d4[0]);
    float go = cur.w + (hiq ? d7[0] : d6[0]);
    float iv = fsig(gi);
    float fv = fsig(gf);
    float gv = fmaf(2.0f, fsig(2.0f*gg), -1.0f);   // tanh
    float ov = fsig(go);
    c = fmaf(fv, c, iv*gv);
    float th = fmaf(2.0f, fsig(2.0f*c), -1.0f);    // tanh(c)
    float hn = ov*th;
    hs[j] = (_Float16)hn;                          // ds_write_b16 (dups identical)
    Lt[n*64 + l] = hn;                             // full-wave store (cols 0..31 used)
  }
}

// ---------------------------------------------------------------- scores[t*2048+n] = lstm[t,n,:]@Wa
__global__ __launch_bounds__(256) void k_score(const float* __restrict__ L64,
                                               const float* __restrict__ Wa,
                                               float* __restrict__ scores){
  const int gid = blockIdx.x*256 + threadIdx.x;   // t*2048 + n, 32768 total
  const float4* row = (const float4*)(L64 + (size_t)gid*64);
  const float4* wa4 = (const float4*)Wa;
  float s = 0.f;
  #pragma unroll
  for (int qq = 0; qq < 8; qq++){
    float4 hv = row[qq], wv = wa4[qq];
    s += hv.x*wv.x + hv.y*wv.y + hv.z*wv.z + hv.w*wv.w;
  }
  scores[gid] = s;
}

// ---------------------------------------------------------------- softmax attention pool
__global__ __launch_bounds__(256) void k_attn(const float* __restrict__ scores,
                                              const float* __restrict__ L64,
                                              float* __restrict__ out){
  const int gid = blockIdx.x*256 + threadIdx.x;   // n*32 + k
  const int k = gid & 31, n = gid >> 5;
  float sc[16]; float mx = -1e30f;
  #pragma unroll
  for (int t = 0; t < 16; t++){ float v = scores[(t << 11) + n]; sc[t] = v; mx = fmaxf(mx, v); }
  float sum = 0.f;
  #pragma unroll
  for (int t = 0; t < 16; t++){ float e = __expf(sc[t] - mx); sc[t] = e; sum += e; }
  const float inv = frcp(sum);
  float acc = 0.f;
  #pragma unroll
  for (int t = 0; t < 16; t++) acc += sc[t]*L64[((size_t)((t << 11) + n))*64 + k];
  out[gid] = acc*inv;
}

// ---------------------------------------------------------------- launch
extern "C" void kernel_launch(void* const* d_in, const int* in_sizes, int n_in,
                              void* d_out, int out_size, void* d_ws, size_t ws_size,
                              hipStream_t stream){
  (void)in_sizes; (void)n_in; (void)out_size; (void)ws_size;
  const float*   x   = (const float*)d_in[0];
  const float*   adj = (const float*)d_in[1];
  const uint8_t* ego = (const uint8_t*)d_in[2];
  const float*   W1  = (const float*)d_in[3];
  const float*   b1  = (const float*)d_in[4];
  const float*   W2  = (const float*)d_in[5];
  const float*   b2  = (const float*)d_in[6];
  const float*   Wih = (const float*)d_in[7];
  const float*   Whh = (const float*)d_in[8];
  const float*   bih = (const float*)d_in[9];
  const float*   bhh = (const float*)d_in[10];
  const float*   Wa  = (const float*)d_in[11];
  // d_in[12] = ba: softmax is shift-invariant, unused
  float* out = (float*)d_out;
  char* ws = (char*)d_ws;

  float*    m      = (float*)(ws);                  // 128 KB
  float*    dinv   = (float*)(ws + 131072);         // 128 KB
  int*      cnt    = (int*)  (ws + 262144);         // 128 KB
  uint16_t* idx    = (uint16_t*)(ws + 393216);      // 6 MB
  float*    v      = (float*)(ws + 6684672);        // 8 MB   (v2; later reused as L64)
  float*    h      = (float*)(ws + 15073280);       // 8 MB   (h1 then h2; later scores)
  float*    P4     = (float*)(ws + 23461888);       // 16 MB
  float*    L64    = v;                             // v dead after k_agg2
  float*    scores = h;                             // h dead after k_lstmpre

  k_mask    <<<16,    256, 0, stream>>>(ego, m, cnt);
  k_sparsify<<<1024,  256, 0, stream>>>(adj, cnt, idx);
  k_dinv    <<<128,   256, 0, stream>>>(cnt, idx, m, dinv);
  k_gcn1    <<<8192,  256, 0, stream>>>(x, W1, b1, cnt, idx, dinv, h);
  k_v2      <<<8192,  256, 0, stream>>>(h, W2, dinv, v);
  k_agg2    <<<8192,  256, 0, stream>>>(v, cnt, idx, dinv, m, b2, h);
  k_lstmpre <<<512,   256, 0, stream>>>(h, Wih, bih, bhh, P4);
  k_lstm    <<<16,    64,  0, stream>>>(P4, Whh, L64);
  k_score   <<<128,   256, 0, stream>>>(L64, Wa, scores);
  k_attn    <<<256,   256, 0, stream>>>(scores, L64, out);
}